// Round 1
// baseline (48.436 us; speedup 1.0000x reference)
//
#include <hip/hip_runtime.h>

// ---- problem constants ----
// B=16, N=512, D_MODEL=256, NUM_RBF=50, CUTOFF=12
// delta = 12/49, width = 2*delta, inv_w2 = 2401/576
// S  = sqrt(inv_w2 * log2(e)) = 2.4522916
// DS = delta * S              = 0.60056098
#define S_C  2.4522916f
#define DS_C 0.60056098f

__device__ __forceinline__ float fast_exp2(float x) {
#if __has_builtin(__builtin_amdgcn_exp2f)
    return __builtin_amdgcn_exp2f(x);
#else
    float r;
    asm("v_exp_f32 %0, %1" : "=v"(r) : "v"(x));
    return r;
#endif
}

// One wave per output row (b,i). Lanes split the 512 neighbors (8 each),
// 50 RBF accumulators live in VGPRs, cross-lane reduce via per-wave LDS matrix.
template <bool FUSED>
__global__ __launch_bounds__(256)
void rbf_mean_kernel(const float* __restrict__ pos,
                     float* __restrict__ meanout,   // !FUSED
                     const int* __restrict__ an,    // FUSED only
                     const float* __restrict__ te,
                     const float* __restrict__ pw,
                     const float* __restrict__ pb,
                     float* __restrict__ out)
{
    __shared__ float red[4][64 * 50];   // [wave][lane*50 + k], stride 50
    __shared__ float ms[4][52];         // broadcast buffer (FUSED path)

    const int w    = threadIdx.x >> 6;
    const int lane = threadIdx.x & 63;
    const int row  = blockIdx.x * 4 + w;    // 0..8191
    const int b    = row >> 9;               // N = 512
    const int i    = row & 511;

    const float* posb = pos + (size_t)b * 512 * 3;

    // preload this lane's 8 neighbor positions (registers, static indices)
    float jx[8], jy[8], jz[8];
#pragma unroll
    for (int jj = 0; jj < 8; ++jj) {
        const int j = jj * 64 + lane;
        jx[jj] = posb[j * 3 + 0];
        jy[jj] = posb[j * 3 + 1];
        jz[jj] = posb[j * 3 + 2];
    }
    const float pix = posb[i * 3 + 0];
    const float piy = posb[i * 3 + 1];
    const float piz = posb[i * 3 + 2];

    float acc[50];
#pragma unroll
    for (int k = 0; k < 50; ++k) acc[k] = 0.0f;

#pragma unroll
    for (int jj = 0; jj < 8; ++jj) {
        const float dx = pix - jx[jj];
        const float dy = piy - jy[jj];
        const float dz = piz - jz[jj];
        const float d2 = fmaf(dx, dx, fmaf(dy, dy, fmaf(dz, dz, 1e-8f)));
        const float dS = sqrtf(d2) * S_C;   // exp(-(d-c)^2/w^2) = 2^(-(d*S - k*DS)^2)
#pragma unroll
        for (int k = 0; k < 50; ++k) {
            const float u = dS - (float)k * DS_C;  // literal add per k
            acc[k] += fast_exp2(-(u * u));
        }
    }

    // ---- cross-lane reduction: per-wave LDS matrix [lane][k], stride 50 ----
    {
        float* myrow = &red[w][lane * 50];
#pragma unroll
        for (int k = 0; k < 50; k += 2) {
            *reinterpret_cast<float2*>(myrow + k) = make_float2(acc[k], acc[k + 1]);
        }
    }
    __syncthreads();

    float meanv = 0.0f;
    if (lane < 50) {
        const float* col = &red[w][lane];
        float s0 = 0.f, s1 = 0.f, s2 = 0.f, s3 = 0.f;
#pragma unroll
        for (int l = 0; l < 64; l += 4) {
            s0 += col[(l + 0) * 50];
            s1 += col[(l + 1) * 50];
            s2 += col[(l + 2) * 50];
            s3 += col[(l + 3) * 50];
        }
        meanv = ((s0 + s1) + (s2 + s3)) * (1.0f / 512.0f);
    }

    if (!FUSED) {
        if (lane < 50) meanout[(size_t)row * 50 + lane] = meanv;
        return;
    }

    // ---- fallback fused epilogue (only if d_ws is too small) ----
    if (lane < 50) ms[w][lane] = meanv;
    __syncthreads();

    const int tok = an[row];
    float4 o = reinterpret_cast<const float4*>(pb)[lane];
    const float4 t = reinterpret_cast<const float4*>(te + (size_t)tok * 256)[lane];
    o.x += t.x; o.y += t.y; o.z += t.z; o.w += t.w;
#pragma unroll
    for (int k = 0; k < 50; ++k) {
        const float mk = ms[w][k];  // uniform LDS broadcast
        const float4 w4 = reinterpret_cast<const float4*>(pw + k * 256)[lane];
        o.x = fmaf(mk, w4.x, o.x);
        o.y = fmaf(mk, w4.y, o.y);
        o.z = fmaf(mk, w4.z, o.z);
        o.w = fmaf(mk, w4.w, o.w);
    }
    reinterpret_cast<float4*>(out)[(size_t)row * 64 + lane] = o;
}

// out[row][:] = te[an[row]][:] + pb[:] + mean[row][:] @ pw
// One wave handles 8 rows x 256 cols (float4/lane); pw row reused across the
// 8 rows from registers; mean reads are wave-uniform (scalar path).
__global__ __launch_bounds__(256)
void proj_kernel(const float* __restrict__ mean,
                 const int* __restrict__ an,
                 const float* __restrict__ te,
                 const float* __restrict__ pw,
                 const float* __restrict__ pb,
                 float* __restrict__ out)
{
    const int w    = threadIdx.x >> 6;
    const int lane = threadIdx.x & 63;
    int wid = blockIdx.x * 4 + w;                       // 0..1023
    wid = __builtin_amdgcn_readfirstlane(wid);          // force SGPR
    const int row0 = wid * 8;

    const float4 bias = reinterpret_cast<const float4*>(pb)[lane];
    float4 o[8];
#pragma unroll
    for (int r = 0; r < 8; ++r) {
        const int tok = an[row0 + r];                   // wave-uniform
        const float4 t = reinterpret_cast<const float4*>(te + (size_t)tok * 256)[lane];
        o[r].x = bias.x + t.x; o[r].y = bias.y + t.y;
        o[r].z = bias.z + t.z; o[r].w = bias.w + t.w;
    }
#pragma unroll
    for (int k = 0; k < 50; ++k) {
        const float4 w4 = reinterpret_cast<const float4*>(pw + (size_t)k * 256)[lane];
#pragma unroll
        for (int r = 0; r < 8; ++r) {
            const float mk = mean[(size_t)(row0 + r) * 50 + k];  // wave-uniform
            o[r].x = fmaf(mk, w4.x, o[r].x);
            o[r].y = fmaf(mk, w4.y, o[r].y);
            o[r].z = fmaf(mk, w4.z, o[r].z);
            o[r].w = fmaf(mk, w4.w, o[r].w);
        }
    }
#pragma unroll
    for (int r = 0; r < 8; ++r)
        reinterpret_cast<float4*>(out)[(size_t)(row0 + r) * 64 + lane] = o[r];
}

extern "C" void kernel_launch(void* const* d_in, const int* in_sizes, int n_in,
                              void* d_out, int out_size, void* d_ws, size_t ws_size,
                              hipStream_t stream)
{
    const int*   an  = (const int*)  d_in[0];   // [16,512] int32
    const float* pos = (const float*)d_in[1];   // [16,512,3]
    const float* te  = (const float*)d_in[2];   // [100,256]
    const float* pw  = (const float*)d_in[3];   // [50,256]
    const float* pb  = (const float*)d_in[4];   // [256]
    float* out = (float*)d_out;                  // [16,512,256]

    const size_t mean_bytes = (size_t)8192 * 50 * sizeof(float);
    if (ws_size >= mean_bytes) {
        float* mean = (float*)d_ws;
        rbf_mean_kernel<false><<<2048, 256, 0, stream>>>(pos, mean, nullptr, nullptr,
                                                         nullptr, nullptr, nullptr);
        proj_kernel<<<256, 256, 0, stream>>>(mean, an, te, pw, pb, out);
    } else {
        rbf_mean_kernel<true><<<2048, 256, 0, stream>>>(pos, nullptr, an, te, pw, pb, out);
    }
}

// Round 2
// 35.072 us; speedup vs baseline: 1.3811x; 1.3811x over previous
//
#include <hip/hip_runtime.h>

// ---- problem constants ----
// B=16, N=512, D_MODEL=256, NUM_RBF=50, CUTOFF=12
// delta = 12/49, width = 2*delta
// S   = sqrt( (1/width^2) * log2(e) ) = 2.452293
// DS  = delta * S = 0.6005611
// DS2 = DS^2      = 0.3606733
// C4  = 4*DS      = 2.4022444
#define S_C   2.4522916f
#define DS_C  0.60056098f
#define DS2_C 0.36067334f
#define C4_C  2.40224392f

typedef float v2f __attribute__((ext_vector_type(2)));

__device__ __forceinline__ float fast_exp2(float x) {
#if __has_builtin(__builtin_amdgcn_exp2f)
    return __builtin_amdgcn_exp2f(x);
#else
    float r;
    asm("v_exp_f32 %0, %1" : "=v"(r) : "v"(x));
    return r;
#endif
}
__device__ __forceinline__ float fast_sqrt(float x) {
#if __has_builtin(__builtin_amdgcn_sqrtf)
    return __builtin_amdgcn_sqrtf(x);
#else
    return sqrtf(x);
#endif
}

// One wave per output row (b,i). Lanes split the 512 neighbors (8 each).
// RBF over k via packed stride-2 multiplicative recurrence:
//   g_k = 2^{-(dS - k*DS)^2},  g_{k+2} = g_k * A * 2^{-(4k+4)*DS2},  A = 2^{4*DS*dS}
// reseeded from exp2 every 10 k's (5 chunks), even/odd chains packed in v2f.
template <bool FUSED>
__global__ __launch_bounds__(256)
void rbf_mean_kernel(const float* __restrict__ pos,
                     float* __restrict__ meanout,   // !FUSED
                     const int* __restrict__ an,    // FUSED only
                     const float* __restrict__ te,
                     const float* __restrict__ pw,
                     const float* __restrict__ pb,
                     float* __restrict__ out)
{
    __shared__ float red[4][64 * 50];   // [wave][lane*50 + k], stride 50
    __shared__ float ms[4][52];

    const int w    = threadIdx.x >> 6;
    const int lane = threadIdx.x & 63;
    const int row  = blockIdx.x * 4 + w;    // 0..8191
    const int b    = row >> 9;              // N = 512
    const int i    = row & 511;

    const float* posb = pos + (size_t)b * 512 * 3;

    // per-thread one-time constants (all from one exp2 + a few muls)
    const float Bx = fast_exp2(-4.0f * DS2_C);   // 2^{-4*DS2}
    const float By = Bx * Bx;                    // 2^{-8*DS2}
    const v2f  Bp  = {Bx, By};
    const float R1 = By, R2 = R1 * R1, R3 = R2 * R1;
    const v2f  Rp[4] = {{1.0f, 1.0f}, {R1, R1}, {R2, R2}, {R3, R3}};
    const float P1 = R2 * R2 * R1;               // 2^{-40*DS2}
    const float P2 = P1 * P1, P3 = P2 * P1, P4 = P2 * P2;
    const float P[5] = {1.0f, P1, P2, P3, P4};
    const float kc[5] = {0.0f, 10.f * DS_C, 20.f * DS_C, 30.f * DS_C, 40.f * DS_C};

    // preload this lane's 8 neighbor positions
    float jx[8], jy[8], jz[8];
#pragma unroll
    for (int jj = 0; jj < 8; ++jj) {
        const int j = jj * 64 + lane;
        jx[jj] = posb[j * 3 + 0];
        jy[jj] = posb[j * 3 + 1];
        jz[jj] = posb[j * 3 + 2];
    }
    const float pix = posb[i * 3 + 0];
    const float piy = posb[i * 3 + 1];
    const float piz = posb[i * 3 + 2];

    v2f acc[5][5];   // acc[c][t] = (g_{10c+2t}, g_{10c+2t+1})
#pragma unroll
    for (int c = 0; c < 5; ++c)
#pragma unroll
        for (int t = 0; t < 5; ++t) acc[c][t] = (v2f){0.0f, 0.0f};

#pragma unroll
    for (int jj = 0; jj < 8; ++jj) {
        const float dx = pix - jx[jj];
        const float dy = piy - jy[jj];
        const float dz = piz - jz[jj];
        const float d2 = fmaf(dx, dx, fmaf(dy, dy, fmaf(dz, dz, 1e-8f)));
        float dS = fast_sqrt(d2) * S_C;
        dS = fminf(dS, 42.0f);               // all k give exact 0 beyond; keeps A finite
        const float A = fast_exp2(dS * C4_C);

#pragma unroll
        for (int c = 0; c < 5; ++c) {
            const float u  = dS - kc[c];
            const float ge = fast_exp2(-(u * u));
            const float uo = u - DS_C;
            const float go = fast_exp2(-(uo * uo));
            const float Ac = A * P[c];
            const v2f  AcB = Bp * (v2f){Ac, Ac};
            v2f g = {ge, go};
            acc[c][0] += g;
#pragma unroll
            for (int t = 1; t < 5; ++t) {
                const v2f M = AcB * Rp[t - 1];
                g = g * M;
                acc[c][t] += g;
            }
        }
    }

    // ---- cross-lane reduction: per-wave LDS matrix [lane][k], stride 50 ----
    {
        float* myrow = &red[w][lane * 50];
#pragma unroll
        for (int c = 0; c < 5; ++c)
#pragma unroll
            for (int t = 0; t < 5; ++t)
                *reinterpret_cast<v2f*>(myrow + 10 * c + 2 * t) = acc[c][t];
    }
    __syncthreads();

    float meanv = 0.0f;
    if (lane < 50) {
        const float* col = &red[w][lane];
        float s0 = 0.f, s1 = 0.f, s2 = 0.f, s3 = 0.f;
#pragma unroll
        for (int l = 0; l < 64; l += 4) {
            s0 += col[(l + 0) * 50];
            s1 += col[(l + 1) * 50];
            s2 += col[(l + 2) * 50];
            s3 += col[(l + 3) * 50];
        }
        meanv = ((s0 + s1) + (s2 + s3)) * (1.0f / 512.0f);
    }

    if (!FUSED) {
        if (lane < 50) meanout[(size_t)row * 50 + lane] = meanv;
        return;
    }

    // ---- fallback fused epilogue (only if d_ws is too small) ----
    if (lane < 50) ms[w][lane] = meanv;
    __syncthreads();

    const int tok = an[row];
    float4 o = reinterpret_cast<const float4*>(pb)[lane];
    const float4 t = reinterpret_cast<const float4*>(te + (size_t)tok * 256)[lane];
    o.x += t.x; o.y += t.y; o.z += t.z; o.w += t.w;
#pragma unroll
    for (int k = 0; k < 50; ++k) {
        const float mk = ms[w][k];
        const float4 w4 = reinterpret_cast<const float4*>(pw + k * 256)[lane];
        o.x = fmaf(mk, w4.x, o.x);
        o.y = fmaf(mk, w4.y, o.y);
        o.z = fmaf(mk, w4.z, o.z);
        o.w = fmaf(mk, w4.w, o.w);
    }
    reinterpret_cast<float4*>(out)[(size_t)row * 64 + lane] = o;
}

// out[row][:] = te[an[row]][:] + pb[:] + mean[row][:] @ pw
__global__ __launch_bounds__(256)
void proj_kernel(const float* __restrict__ mean,
                 const int* __restrict__ an,
                 const float* __restrict__ te,
                 const float* __restrict__ pw,
                 const float* __restrict__ pb,
                 float* __restrict__ out)
{
    const int w    = threadIdx.x >> 6;
    const int lane = threadIdx.x & 63;
    int wid = blockIdx.x * 4 + w;                       // 0..1023
    wid = __builtin_amdgcn_readfirstlane(wid);          // force SGPR
    const int row0 = wid * 8;

    const float4 bias = reinterpret_cast<const float4*>(pb)[lane];
    float4 o[8];
#pragma unroll
    for (int r = 0; r < 8; ++r) {
        const int tok = an[row0 + r];                   // wave-uniform
        const float4 t = reinterpret_cast<const float4*>(te + (size_t)tok * 256)[lane];
        o[r].x = bias.x + t.x; o[r].y = bias.y + t.y;
        o[r].z = bias.z + t.z; o[r].w = bias.w + t.w;
    }
#pragma unroll
    for (int k = 0; k < 50; ++k) {
        const float4 w4 = reinterpret_cast<const float4*>(pw + (size_t)k * 256)[lane];
#pragma unroll
        for (int r = 0; r < 8; ++r) {
            const float mk = mean[(size_t)(row0 + r) * 50 + k];  // wave-uniform
            o[r].x = fmaf(mk, w4.x, o[r].x);
            o[r].y = fmaf(mk, w4.y, o[r].y);
            o[r].z = fmaf(mk, w4.z, o[r].z);
            o[r].w = fmaf(mk, w4.w, o[r].w);
        }
    }
#pragma unroll
    for (int r = 0; r < 8; ++r)
        reinterpret_cast<float4*>(out)[(size_t)(row0 + r) * 64 + lane] = o[r];
}

extern "C" void kernel_launch(void* const* d_in, const int* in_sizes, int n_in,
                              void* d_out, int out_size, void* d_ws, size_t ws_size,
                              hipStream_t stream)
{
    const int*   an  = (const int*)  d_in[0];   // [16,512] int32
    const float* pos = (const float*)d_in[1];   // [16,512,3]
    const float* te  = (const float*)d_in[2];   // [100,256]
    const float* pw  = (const float*)d_in[3];   // [50,256]
    const float* pb  = (const float*)d_in[4];   // [256]
    float* out = (float*)d_out;                  // [16,512,256]

    const size_t mean_bytes = (size_t)8192 * 50 * sizeof(float);
    if (ws_size >= mean_bytes) {
        float* mean = (float*)d_ws;
        rbf_mean_kernel<false><<<2048, 256, 0, stream>>>(pos, mean, nullptr, nullptr,
                                                         nullptr, nullptr, nullptr);
        proj_kernel<<<256, 256, 0, stream>>>(mean, an, te, pw, pb, out);
    } else {
        rbf_mean_kernel<true><<<2048, 256, 0, stream>>>(pos, nullptr, an, te, pw, pb, out);
    }
}

// Round 3
// 26.638 us; speedup vs baseline: 1.8183x; 1.3166x over previous
//
#include <hip/hip_runtime.h>

// ---- problem constants ----
// B=16, N=512, D_MODEL=256, NUM_RBF=50, CUTOFF=12
// delta = 12/49, width = 2*delta
// S = sqrt(log2(e))/width-scale = 2.45229158;  D = delta*S = sqrt(log2 e)/2
// Key identity: 4*D^2 = log2(e)  =>  2^{-m*D^2} = e^{-m/4}
#define S_C     2.45229158f
#define TWO_DS  1.20112241f   /* 2*D = sqrt(log2 e) */

typedef float v2f __attribute__((ext_vector_type(2)));

__device__ __forceinline__ float fast_exp2(float x) {
#if __has_builtin(__builtin_amdgcn_exp2f)
    return __builtin_amdgcn_exp2f(x);
#else
    float r;
    asm("v_exp_f32 %0, %1" : "=v"(r) : "v"(x));
    return r;
#endif
}
__device__ __forceinline__ float fast_sqrt(float x) {
#if __has_builtin(__builtin_amdgcn_sqrtf)
    return __builtin_amdgcn_sqrtf(x);
#else
    return sqrtf(x);
#endif
}

// chunk constants (c = 0..4), all exact powers of e^-1:
__constant__ const float NEGC[5] = {0.0f, -6.00561204f, -12.0112241f, -18.0168361f, -24.0224482f};
// e^{-5c}  (A_c  = A' * e^{-5c})
#define E5_1 6.73794700e-3f
#define E5_2 4.53999298e-5f
#define E5_3 3.05902321e-7f
#define E5_4 2.06115362e-9f
// e^{-10c} (A_c^2 = A * e^{-10c})
#define E10_1 4.53999298e-5f
#define E10_2 2.06115362e-9f
#define E10_3 9.35762297e-14f
#define E10_4 4.24835426e-18f

// One wave per output row (b,i). Lanes split the 512 neighbors (8 each).
// Within chunk c (10 k's): g_{k0+r} = t0 * Ac^r * e^{-r^2/4}
//   t0 = 2^{-u^2}, u = dS - 10c*D, Ac = 2^{2*D*u} = A' * e^{-5c}
// Pure geometric chain in t'' (e^{-r^2/4} factored out of the j-sum,
// applied once per wave at the end).
template <bool FUSED>
__global__ __launch_bounds__(256)
void rbf_mean_kernel(const float* __restrict__ pos,
                     float* __restrict__ meanout,   // !FUSED
                     const int* __restrict__ an,    // FUSED only
                     const float* __restrict__ te,
                     const float* __restrict__ pw,
                     const float* __restrict__ pb,
                     float* __restrict__ out)
{
    __shared__ v2f red2[4][32 * 25];   // [wave][row(=lane/2)*25 + m]
    __shared__ float ms[4][52];

    const int w    = threadIdx.x >> 6;
    const int lane = threadIdx.x & 63;
    const int row  = blockIdx.x * 4 + w;    // 0..8191
    const int b    = row >> 9;              // N = 512
    const int i    = row & 511;

    const float* posb = pos + (size_t)b * 512 * 3;

    // preload this lane's 8 neighbor positions
    float jx[8], jy[8], jz[8];
#pragma unroll
    for (int jj = 0; jj < 8; ++jj) {
        const int j = jj * 64 + lane;
        jx[jj] = posb[j * 3 + 0];
        jy[jj] = posb[j * 3 + 1];
        jz[jj] = posb[j * 3 + 2];
    }
    const float pix = posb[i * 3 + 0];
    const float piy = posb[i * 3 + 1];
    const float piz = posb[i * 3 + 2];

    v2f acc[25];   // acc[5c+t] = sum_j {t''_{2t}, t''_{2t+1}} of chunk c
#pragma unroll
    for (int m = 0; m < 25; ++m) acc[m] = (v2f){0.0f, 0.0f};

#pragma unroll
    for (int jj = 0; jj < 8; ++jj) {
        const float dx = pix - jx[jj];
        const float dy = piy - jy[jj];
        const float dz = piz - jz[jj];
        const float d2 = fmaf(dx, dx, fmaf(dy, dy, fmaf(dz, dz, 1e-8f)));
        float dS = fast_sqrt(d2) * S_C;
        dS = fminf(dS, 42.0f);            // true values identically 0 beyond
        const float Ap = fast_exp2(dS * TWO_DS);   // A' = 2^{2*D*dS}
        const float A  = Ap * Ap;

#pragma unroll
        for (int c = 0; c < 5; ++c) {
            const float u  = dS + NEGC[c];
            const float t0 = fast_exp2(-(u * u));
            const float Ac  = (c == 0) ? Ap :
                              (c == 1) ? Ap * E5_1 :
                              (c == 2) ? Ap * E5_2 :
                              (c == 3) ? Ap * E5_3 : Ap * E5_4;
            const float Ac2 = (c == 0) ? A :
                              (c == 1) ? A * E10_1 :
                              (c == 2) ? A * E10_2 :
                              (c == 3) ? A * E10_3 : A * E10_4;
            v2f g = {t0, t0 * Ac};
            acc[5 * c + 0] += g;
            const v2f M = {Ac2, Ac2};
#pragma unroll
            for (int t = 1; t < 5; ++t) {
                g = g * M;
                acc[5 * c + t] += g;
            }
        }
    }

    // apply the j-independent e^{-r^2/4} factors once (r = local index 2t,2t+1)
    {
        const v2f QP[5] = {{1.0f,            0.778800783f},
                           {0.367879441f,    0.105399225f},
                           {1.83156389e-2f,  1.93045414e-3f},
                           {1.23409804e-4f,  4.78511739e-6f},
                           {1.12535175e-7f,  1.60522806e-9f}};
#pragma unroll
        for (int m = 0; m < 25; ++m) acc[m] = acc[m] * QP[m % 5];
    }

    // ---- stage 1: pair-reduce via shfl_xor(1), halves the LDS matrix ----
#pragma unroll
    for (int m = 0; m < 25; ++m) {
        const float lx = __shfl_xor(acc[m].x, 1);
        const float ly = __shfl_xor(acc[m].y, 1);
        acc[m] += (v2f){lx, ly};
    }
    if ((lane & 1) == 0) {
        v2f* myrow = &red2[w][(lane >> 1) * 25];
#pragma unroll
        for (int m = 0; m < 25; ++m) myrow[m] = acc[m];
    }
    __syncthreads();

    float meanv = 0.0f;
    if (lane < 50) {
        const float* col = (const float*)&red2[w][0] + lane;
        float s0 = 0.f, s1 = 0.f, s2 = 0.f, s3 = 0.f;
#pragma unroll
        for (int r = 0; r < 32; r += 4) {
            s0 += col[(r + 0) * 50];
            s1 += col[(r + 1) * 50];
            s2 += col[(r + 2) * 50];
            s3 += col[(r + 3) * 50];
        }
        meanv = ((s0 + s1) + (s2 + s3)) * (1.0f / 512.0f);
    }

    if (!FUSED) {
        if (lane < 50) meanout[(size_t)row * 50 + lane] = meanv;
        return;
    }

    // ---- fallback fused epilogue (only if d_ws is too small) ----
    if (lane < 50) ms[w][lane] = meanv;
    __syncthreads();

    const int tok = an[row];
    float4 o = reinterpret_cast<const float4*>(pb)[lane];
    const float4 t = reinterpret_cast<const float4*>(te + (size_t)tok * 256)[lane];
    o.x += t.x; o.y += t.y; o.z += t.z; o.w += t.w;
#pragma unroll
    for (int k = 0; k < 50; ++k) {
        const float mk = ms[w][k];
        const float4 w4 = reinterpret_cast<const float4*>(pw + k * 256)[lane];
        o.x = fmaf(mk, w4.x, o.x);
        o.y = fmaf(mk, w4.y, o.y);
        o.z = fmaf(mk, w4.z, o.z);
        o.w = fmaf(mk, w4.w, o.w);
    }
    reinterpret_cast<float4*>(out)[(size_t)row * 64 + lane] = o;
}

// out[row][:] = te[an[row]][:] + pb[:] + mean[row][:] @ pw
// 4 rows per wave, 2048 waves (2/SIMD) -> pw L2 traffic 105 MB, latency hidden.
__global__ __launch_bounds__(256)
void proj_kernel(const float* __restrict__ mean,
                 const int* __restrict__ an,
                 const float* __restrict__ te,
                 const float* __restrict__ pw,
                 const float* __restrict__ pb,
                 float* __restrict__ out)
{
    const int w    = threadIdx.x >> 6;
    const int lane = threadIdx.x & 63;
    int wid = blockIdx.x * 4 + w;                       // 0..2047
    wid = __builtin_amdgcn_readfirstlane(wid);          // force SGPR
    const int row0 = wid * 4;

    const float4 bias = reinterpret_cast<const float4*>(pb)[lane];
    float4 o[4];
#pragma unroll
    for (int r = 0; r < 4; ++r) {
        const int tok = an[row0 + r];                   // wave-uniform
        const float4 t = reinterpret_cast<const float4*>(te + (size_t)tok * 256)[lane];
        o[r].x = bias.x + t.x; o[r].y = bias.y + t.y;
        o[r].z = bias.z + t.z; o[r].w = bias.w + t.w;
    }
#pragma unroll
    for (int k = 0; k < 50; ++k) {
        const float4 w4 = reinterpret_cast<const float4*>(pw + (size_t)k * 256)[lane];
#pragma unroll
        for (int r = 0; r < 4; ++r) {
            const float mk = mean[(size_t)(row0 + r) * 50 + k];  // wave-uniform
            o[r].x = fmaf(mk, w4.x, o[r].x);
            o[r].y = fmaf(mk, w4.y, o[r].y);
            o[r].z = fmaf(mk, w4.z, o[r].z);
            o[r].w = fmaf(mk, w4.w, o[r].w);
        }
    }
#pragma unroll
    for (int r = 0; r < 4; ++r)
        reinterpret_cast<float4*>(out)[(size_t)(row0 + r) * 64 + lane] = o[r];
}

extern "C" void kernel_launch(void* const* d_in, const int* in_sizes, int n_in,
                              void* d_out, int out_size, void* d_ws, size_t ws_size,
                              hipStream_t stream)
{
    const int*   an  = (const int*)  d_in[0];   // [16,512] int32
    const float* pos = (const float*)d_in[1];   // [16,512,3]
    const float* te  = (const float*)d_in[2];   // [100,256]
    const float* pw  = (const float*)d_in[3];   // [50,256]
    const float* pb  = (const float*)d_in[4];   // [256]
    float* out = (float*)d_out;                  // [16,512,256]

    const size_t mean_bytes = (size_t)8192 * 50 * sizeof(float);
    if (ws_size >= mean_bytes) {
        float* mean = (float*)d_ws;
        rbf_mean_kernel<false><<<2048, 256, 0, stream>>>(pos, mean, nullptr, nullptr,
                                                         nullptr, nullptr, nullptr);
        proj_kernel<<<512, 256, 0, stream>>>(mean, an, te, pw, pb, out);
    } else {
        rbf_mean_kernel<true><<<2048, 256, 0, stream>>>(pos, nullptr, an, te, pw, pb, out);
    }
}